// Round 6
// baseline (298.733 us; speedup 1.0000x reference)
//
#include <hip/hip_runtime.h>
#include <cstddef>
#include <cstdint>

// ---------------------------------------------------------------------------
// MAB fused block. B=4 N=M=2048 C=1024 H=16 d=64. bf16 MFMA internally.
// R12: attn is LDS-read-BW-bound (8192 ds_read_b128/CU ~= 35-40us of the 77us
// wall). V moved OFF LDS: gemm_qkv z=2 now writes V^T in FRAGMENT ORDER
// (Vt2[bh][tile][j=c*4+dvb][lane][16B]), so attn loads vf via perfectly
// coalesced global dwordx4 from the (XCD-swizzle-hot) L2/L1 -- a different
// pipe than LDS. LDS reads per block-tile halve (K only); Vs buffers deleted
// (LDS 64->32 KB); V-side bank conflicts gone. vf issued in two groups
// (chunks 0-1 at tile top, 2-3 after S-MFMA) so S-phase covers L2 latency;
// stage loads queue behind -> compiler emits counted (partial) vmcnt waits.
// Sigma contraction algebra unchanged. R11 XCD swizzles kept everywhere.
// ---------------------------------------------------------------------------

typedef unsigned short ushort_t;
typedef __attribute__((ext_vector_type(8))) short bf16x8;
typedef __attribute__((ext_vector_type(4))) float floatx4;
typedef __attribute__((ext_vector_type(2))) float f32x2;
typedef __attribute__((ext_vector_type(2))) __bf16 b16x2;
typedef __attribute__((ext_vector_type(4))) unsigned short us4;

__device__ __forceinline__ ushort_t f2bf(float x) {   // RNE
  union { float f; unsigned u; } v; v.f = x;
  unsigned r = v.u + 0x7FFFu + ((v.u >> 16) & 1u);
  return (ushort_t)(r >> 16);
}
__device__ __forceinline__ float bf2f(ushort_t x) {
  union { unsigned u; float f; } v; v.u = ((unsigned)x) << 16;
  return v.f;
}
// pack two f32 -> [bf16(b):bf16(a)] via +0x8000 + v_perm (round-half-up)
__device__ __forceinline__ unsigned pk2(float a, float b) {
  union { float f; unsigned u; } x, y; x.f = a; y.f = b;
  return __builtin_amdgcn_perm(y.u + 0x8000u, x.u + 0x8000u, 0x07060302u);
}
// pack two f32 -> bf16 pair via compiler (v_cvt_pk_bf16_f32, RNE)
__device__ __forceinline__ unsigned pk2c(float a, float b) {
  union { b16x2 v; unsigned u; } r;
  r.v = __builtin_convertvector((f32x2){a, b}, b16x2);
  return r.u;
}
__device__ __forceinline__ floatx4 mfma16(bf16x8 a, bf16x8 b, floatx4 c) {
  return __builtin_amdgcn_mfma_f32_16x16x32_bf16(a, b, c, 0, 0, 0);
}
__device__ __forceinline__ void gld_lds16(const void* g, void* l) {
  __builtin_amdgcn_global_load_lds(
      (const __attribute__((address_space(1))) unsigned int*)g,
      (__attribute__((address_space(3))) unsigned int*)l, 16, 0, 0);
}

// ---------------------------------------------------------------------------
// f32 -> bf16, 8 elems/thread, 6 tensors by blockIdx.z (Q,K,Wq,Wk,Wv,Wo).
// ---------------------------------------------------------------------------
__global__ void cvt6(const float* __restrict__ i0, const float* __restrict__ i1,
                     const float* __restrict__ i2, const float* __restrict__ i3,
                     const float* __restrict__ i4, const float* __restrict__ i5,
                     ushort_t* __restrict__ o0, ushort_t* __restrict__ o1,
                     ushort_t* __restrict__ o2, ushort_t* __restrict__ o3,
                     ushort_t* __restrict__ o4, ushort_t* __restrict__ o5) {
  int z = blockIdx.z;
  const float* in = z == 0 ? i0 : z == 1 ? i1 : z == 2 ? i2 : z == 3 ? i3 : z == 4 ? i4 : i5;
  ushort_t* out = z == 0 ? o0 : z == 1 ? o1 : z == 2 ? o2 : z == 3 ? o3 : z == 4 ? o4 : o5;
  int n8 = (z < 2) ? 1048576 : 131072;
  int i = blockIdx.x * 256 + threadIdx.x;
  if (i < n8) {
    const float4* p = (const float4*)in + (size_t)i * 2;
    float4 a = p[0], b = p[1];
    uint4 o;
    o.x = pk2(a.x, a.y); o.y = pk2(a.z, a.w);
    o.z = pk2(b.x, b.y); o.w = pk2(b.z, b.w);
    *((uint4*)out + i) = o;
  }
}

// ---------------------------------------------------------------------------
// Fused QKV projections. z=0: Qp; z=1: Kp; z=2: Vt2 (bf16 V^T in attn
// fragment order). Vt2 elem addr = bh*131072 + t*8192 + (c*4+dvb)*512
//   + (kg*16+rq)*8 + hi*4 + rr, holding V^T[dv=dvb*16+rq][kv =
//   t*128 + c*32 + hi*16 + kg*4 + rr]  (bh = b*16+h, dv/h from col).
// 128x128 tile, BK=64, 3-bit XOR chunk swizzle, XCD swizzle on grid.
// ---------------------------------------------------------------------------
__global__ __launch_bounds__(256, 2)
void gemm_qkv(const ushort_t* __restrict__ Qb, const ushort_t* __restrict__ Kb,
              const ushort_t* __restrict__ Wqb, const ushort_t* __restrict__ Wkb,
              const ushort_t* __restrict__ Wvb,
              const float* __restrict__ bq, const float* __restrict__ bk,
              const float* __restrict__ bv,
              ushort_t* __restrict__ Qp, ushort_t* __restrict__ Kp,
              ushort_t* __restrict__ Vt)
{
  const int Kd = 1024, Nn = 1024;
  const int z = blockIdx.z;
  const ushort_t* Ab = (z == 0) ? Qb : Kb;
  const ushort_t* Bw = (z == 0) ? Wqb : (z == 1) ? Wkb : Wvb;
  const float* bias  = (z == 0) ? bq : (z == 1) ? bk : bv;

  __shared__ __align__(16) ushort_t As[128][64];
  __shared__ __align__(16) ushort_t Bs[128][64];
  const int tid = threadIdx.x;
  const int lane = tid & 63, wave = tid >> 6;
  const int wm = (wave >> 1) * 64, wn = (wave & 1) * 64;
  const int rq = lane & 15, kg = lane >> 4;

  // XCD swizzle: each XCD gets a contiguous 8-row-tile A stripe (2 MB in L2)
  const int wg = blockIdx.x, xcd = wg & 7, slot = wg >> 3;   // slot 0..63
  const int by = xcd * 8 + (slot >> 3);                      // 0..63
  const int bx = slot & 7;                                   // 0..7
  const int row0 = by * 128, col0 = bx * 128;

  const int st_sub = lane >> 3;                 // row within 8-row group
  const int st_cs  = (lane & 7) ^ st_sub;       // swizzled source 16B chunk

  floatx4 acc[4][4];
#pragma unroll
  for (int i = 0; i < 4; ++i)
#pragma unroll
    for (int j = 0; j < 4; ++j) acc[i][j] = (floatx4){0.f, 0.f, 0.f, 0.f};

  for (int k0 = 0; k0 < Kd; k0 += 64) {
    __syncthreads();
#pragma unroll
    for (int r = 0; r < 4; ++r) {
      int i = wave * 4 + r;                     // 0..15, 8 rows each
      int row = i * 8 + st_sub;
      gld_lds16(Ab + (size_t)(row0 + row) * Kd + k0 + st_cs * 8, (ushort_t*)As + i * 512);
      gld_lds16(Bw + (size_t)(col0 + row) * Kd + k0 + st_cs * 8, (ushort_t*)Bs + i * 512);
    }
    __syncthreads();
#pragma unroll
    for (int kq = 0; kq < 2; ++kq) {
      bf16x8 af[4], bfr[4];
#pragma unroll
      for (int mi = 0; mi < 4; ++mi)
        af[mi] = *(const bf16x8*)&As[wm + mi*16 + rq][((kq*4 + kg) ^ (rq & 7)) * 8];
#pragma unroll
      for (int ni = 0; ni < 4; ++ni)
        bfr[ni] = *(const bf16x8*)&Bs[wn + ni*16 + rq][((kq*4 + kg) ^ (rq & 7)) * 8];
#pragma unroll
      for (int mi = 0; mi < 4; ++mi)
#pragma unroll
        for (int ni = 0; ni < 4; ++ni)
          acc[mi][ni] = mfma16(af[mi], bfr[ni], acc[mi][ni]);
    }
  }

  float bv4[4];
#pragma unroll
  for (int ni = 0; ni < 4; ++ni) bv4[ni] = bias[col0 + wn + ni*16 + rq];

  if (z < 2) {
    ushort_t* Cb = (z == 0) ? Qp : Kp;
#pragma unroll
    for (int mi = 0; mi < 4; ++mi)
#pragma unroll
      for (int ni = 0; ni < 4; ++ni)
#pragma unroll
        for (int rr = 0; rr < 4; ++rr) {
          int row = row0 + wm + mi*16 + kg*4 + rr;
          int col = col0 + wn + ni*16 + rq;
          Cb[(size_t)row * Nn + col] = f2bf(acc[mi][ni][rr] + bv4[ni]);
        }
  } else {
    // fragment-ordered Vt2 write (see header comment). acc[mi][ni][rr] is
    // V^T[col][kv = row0+wm+mi*16+kg*4+rr]; hi = mi&1.
#pragma unroll
    for (int mi = 0; mi < 4; ++mi)
#pragma unroll
      for (int ni = 0; ni < 4; ++ni) {
        int col = col0 + wn + ni*16 + rq;       // h*64 + dv
        int h = col >> 6, dvb = (col >> 4) & 3; // dv&15 == rq
        int kvg = row0 + wm + (mi >> 1) * 32;   // b*2048 + kv (32-aligned)
        int bI = kvg >> 11, kv = kvg & 2047;
        int t = kv >> 7, c = (kv >> 5) & 3;
        size_t addr = (size_t)(bI * 16 + h) * 131072 + t * 8192
                    + (c * 4 + dvb) * 512 + (kg * 16 + rq) * 8 + (mi & 1) * 4;
        us4 o = { f2bf(acc[mi][ni][0] + bv4[ni]), f2bf(acc[mi][ni][1] + bv4[ni]),
                  f2bf(acc[mi][ni][2] + bv4[ni]), f2bf(acc[mi][ni][3] + bv4[ni]) };
        *(us4*)(Vt + addr) = o;
      }
  }
}

// ---------------------------------------------------------------------------
// Output GEMM: out = bf2f(Ob) + relu(Ob*Wo^T + bo), f32 out. BK=64.
// Grid (512) with the same XCD swizzle as gemm_qkv.
// ---------------------------------------------------------------------------
__global__ __launch_bounds__(256, 2)
void gemm_out(const ushort_t* __restrict__ Ob, const ushort_t* __restrict__ Bw,
              const float* __restrict__ bias, float* __restrict__ Out)
{
  const int Kd = 1024, Nn = 1024;
  __shared__ __align__(16) ushort_t As[128][64];
  __shared__ __align__(16) ushort_t Bs[128][64];
  const int tid = threadIdx.x;
  const int lane = tid & 63, wave = tid >> 6;
  const int wm = (wave >> 1) * 64, wn = (wave & 1) * 64;
  const int rq = lane & 15, kg = lane >> 4;

  const int wg = blockIdx.x, xcd = wg & 7, slot = wg >> 3;
  const int by = xcd * 8 + (slot >> 3);
  const int bx = slot & 7;
  const int row0 = by * 128, col0 = bx * 128;

  const int st_sub = lane >> 3;
  const int st_cs  = (lane & 7) ^ st_sub;

  floatx4 acc[4][4];
#pragma unroll
  for (int i = 0; i < 4; ++i)
#pragma unroll
    for (int j = 0; j < 4; ++j) acc[i][j] = (floatx4){0.f, 0.f, 0.f, 0.f};

  for (int k0 = 0; k0 < Kd; k0 += 64) {
    __syncthreads();
#pragma unroll
    for (int r = 0; r < 4; ++r) {
      int i = wave * 4 + r;
      int row = i * 8 + st_sub;
      gld_lds16(Ob + (size_t)(row0 + row) * Kd + k0 + st_cs * 8, (ushort_t*)As + i * 512);
      gld_lds16(Bw + (size_t)(col0 + row) * Kd + k0 + st_cs * 8, (ushort_t*)Bs + i * 512);
    }
    __syncthreads();
#pragma unroll
    for (int kq = 0; kq < 2; ++kq) {
      bf16x8 af[4], bfr[4];
#pragma unroll
      for (int mi = 0; mi < 4; ++mi)
        af[mi] = *(const bf16x8*)&As[wm + mi*16 + rq][((kq*4 + kg) ^ (rq & 7)) * 8];
#pragma unroll
      for (int ni = 0; ni < 4; ++ni)
        bfr[ni] = *(const bf16x8*)&Bs[wn + ni*16 + rq][((kq*4 + kg) ^ (rq & 7)) * 8];
#pragma unroll
      for (int mi = 0; mi < 4; ++mi)
#pragma unroll
        for (int ni = 0; ni < 4; ++ni)
          acc[mi][ni] = mfma16(af[mi], bfr[ni], acc[mi][ni]);
    }
  }

  float bv4[4];
#pragma unroll
  for (int ni = 0; ni < 4; ++ni) bv4[ni] = bias[col0 + wn + ni*16 + rq];
#pragma unroll
  for (int mi = 0; mi < 4; ++mi)
#pragma unroll
    for (int ni = 0; ni < 4; ++ni)
#pragma unroll
      for (int rr = 0; rr < 4; ++rr) {
        int row = row0 + wm + mi*16 + kg*4 + rr;
        int col = col0 + wn + ni*16 + rq;
        size_t idx = (size_t)row * Nn + col;
        float pre = acc[mi][ni][rr] + bv4[ni];
        Out[idx] = bf2f(Ob[idx]) + (pre > 0.f ? pre : 0.f);
      }
}

// ---------------------------------------------------------------------------
// Flash attention (no-max softmax). BQ=128, BKV=128, d=64, all bf16.
// Wave w owns q rows [w*32, w*32+32); S^T = K*Q^T over the full 128-kv tile
// (K from dbuf LDS), softmax + P-pack in registers, PV with P in-register and
// V^T fragments loaded DIRECTLY from fragment-ordered global Vt2 (L2/L1-hot,
// perfectly coalesced dwordx4; no LDS involvement for V).
// LDS: 2x Ks 16K = 32 KB. One barrier per K-tile.
// ---------------------------------------------------------------------------
__global__ __launch_bounds__(256, 2)
void attn_kernel(const ushort_t* __restrict__ Qp,
                 const ushort_t* __restrict__ Kp,
                 const ushort_t* __restrict__ Vt,
                 ushort_t* __restrict__ Ob)
{
  const float sc2 = 0.045084439f;  // (1/32) * log2(e)
  const int wg = blockIdx.x, xcd = wg & 7, slot = wg >> 3;   // slot 0..127
  const int bh = xcd * 8 + (slot >> 4);                      // 0..63
  const int qt = slot & 15;                                  // 0..15
  const int b = bh >> 4, h = bh & 15;
  const int q0 = qt * 128;

  __shared__ __align__(16) ushort_t Ks[2][8192];  // K[128][64] per buf

  const int tid = threadIdx.x, lane = tid & 63, wq = tid >> 6;  // wq: q-quarter
  const int rq = lane & 15, kg = lane >> 4;

  const size_t qkbase = (size_t)(b * 2048) * 1024 + h * 64;
  const ushort_t* vbase = Vt + (size_t)bh * 131072 + lane * 8;

  // per-lane staging geometry
  const int sg_sub = lane >> 3;               // row within 8-row group
  const int sg_csk = (lane & 7) ^ sg_sub;     // swizzled 16B chunk (64-col row)

  // stage Q tile (128x64) into Ks[1]
#pragma unroll
  for (int r = 0; r < 4; ++r) {
    int i = wq * 4 + r;
    int row = i * 8 + sg_sub;
    gld_lds16(Qp + qkbase + (size_t)(q0 + row) * 1024 + sg_csk * 8, &Ks[1][i * 512]);
  }
  __syncthreads();

  auto stage = [&](int kt, int bufi) {
    const int kv0 = kt * 128;
#pragma unroll
    for (int r = 0; r < 4; ++r) {
      int i = wq * 4 + r;
      int rowk = i * 8 + sg_sub;
      gld_lds16(Kp + qkbase + (size_t)(kv0 + rowk) * 1024 + sg_csk * 8,
                &Ks[bufi][i * 512]);
    }
  };
  stage(0, 0);

  // preload Q B-frags scaled by sc2 from Ks[1]: aq[ni][kq], q = wq*32+ni*16+rq
  bf16x8 aq[2][2];
#pragma unroll
  for (int ni = 0; ni < 2; ++ni)
#pragma unroll
    for (int kq = 0; kq < 2; ++kq) {
      int row = wq * 32 + ni * 16 + rq;
      int ch = (kq * 4 + kg) ^ (rq & 7);
      bf16x8 t = *(const bf16x8*)&Ks[1][row * 64 + ch * 8];
#pragma unroll
      for (int e = 0; e < 8; ++e)
        t[e] = (short)f2bf(bf2f((ushort_t)t[e]) * sc2);
      aq[ni][kq] = t;
    }

  // ones B-operand for the l row-sum MFMA (permutation-invariant)
  bf16x8 ones;
#pragma unroll
  for (int e = 0; e < 8; ++e) ones[e] = (short)0x3F80;

  const floatx4 zf = (floatx4){0.f, 0.f, 0.f, 0.f};  // loop-invariant zero C

  floatx4 oacc[2][4];
  floatx4 lacc[2];
#pragma unroll
  for (int nb = 0; nb < 2; ++nb) {
    lacc[nb] = (floatx4){0.f,0.f,0.f,0.f};
#pragma unroll
    for (int dvb = 0; dvb < 4; ++dvb) oacc[nb][dvb] = (floatx4){0.f,0.f,0.f,0.f};
  }

  __syncthreads();   // tile 0 landed; all waves done reading Q from Ks[1]

  int cur = 0;
#pragma unroll 2
  for (int kt = 0; kt < 16; ++kt) {
    const ushort_t* vtile = vbase + kt * 8192;

    // V fragment prefetch group 0 (chunks 0,1) -- coalesced global, L2/L1-hot
    bf16x8 vfa[16];
#pragma unroll
    for (int j = 0; j < 8; ++j)
      vfa[j] = *(const bf16x8*)(vtile + j * 512);

    // issue next tile's K stage into the other buffer (overlaps compute)
    if (kt < 15) stage(kt + 1, cur ^ 1);

    // S^T = K * Q^T  (mi = kv block 0..7, ni = q block 0..1)
    floatx4 s[8][2];
    __builtin_amdgcn_s_setprio(1);
    {
      bf16x8 ak[8];
#pragma unroll
      for (int mi = 0; mi < 8; ++mi)
        ak[mi] = *(const bf16x8*)&Ks[cur][(mi * 16 + rq) * 64 + ((kg ^ (rq & 7)) * 8)];
#pragma unroll
      for (int mi = 0; mi < 8; ++mi)
#pragma unroll
        for (int ni = 0; ni < 2; ++ni)
          s[mi][ni] = mfma16(ak[mi], aq[ni][0], zf);      // zero-C, no v_movs
#pragma unroll
      for (int mi = 0; mi < 8; ++mi)
        ak[mi] = *(const bf16x8*)&Ks[cur][(mi * 16 + rq) * 64 + (((4 + kg) ^ (rq & 7)) * 8)];
#pragma unroll
      for (int mi = 0; mi < 8; ++mi)
#pragma unroll
        for (int ni = 0; ni < 2; ++ni)
          s[mi][ni] = mfma16(ak[mi], aq[ni][1], s[mi][ni]);
    }
    __builtin_amdgcn_s_setprio(0);

    // V fragment prefetch group 1 (chunks 2,3)
#pragma unroll
    for (int j = 8; j < 16; ++j)
      vfa[j] = *(const bf16x8*)(vtile + j * 512);

    // exp chunk 0 (mi 0,1); remaining chunks overlap PV MFMAs below
#pragma unroll
    for (int mi = 0; mi < 2; ++mi)
#pragma unroll
      for (int ni = 0; ni < 2; ++ni)
#pragma unroll
        for (int rr = 0; rr < 4; ++rr)
          s[mi][ni][rr] = __builtin_amdgcn_exp2f(s[mi][ni][rr]);

    // O += P V ; l += P 1 : per kv-32 chunk c: pack -> MFMA -> exp(next chunk)
#pragma unroll
    for (int c = 0; c < 4; ++c) {
      union { unsigned u[4]; bf16x8 v; } pa0, pa1;
      pa0.u[0] = pk2c(s[2*c  ][0][0], s[2*c  ][0][1]);
      pa0.u[1] = pk2c(s[2*c  ][0][2], s[2*c  ][0][3]);
      pa0.u[2] = pk2c(s[2*c+1][0][0], s[2*c+1][0][1]);
      pa0.u[3] = pk2c(s[2*c+1][0][2], s[2*c+1][0][3]);
      pa1.u[0] = pk2c(s[2*c  ][1][0], s[2*c  ][1][1]);
      pa1.u[1] = pk2c(s[2*c  ][1][2], s[2*c  ][1][3]);
      pa1.u[2] = pk2c(s[2*c+1][1][0], s[2*c+1][1][1]);
      pa1.u[3] = pk2c(s[2*c+1][1][2], s[2*c+1][1][3]);
      __builtin_amdgcn_s_setprio(1);
#pragma unroll
      for (int dvb = 0; dvb < 4; ++dvb) {
        oacc[0][dvb] = mfma16(pa0.v, vfa[c*4+dvb], oacc[0][dvb]);
        oacc[1][dvb] = mfma16(pa1.v, vfa[c*4+dvb], oacc[1][dvb]);
      }
      lacc[0] = mfma16(pa0.v, ones, lacc[0]);
      lacc[1] = mfma16(pa1.v, ones, lacc[1]);
      __builtin_amdgcn_s_setprio(0);
      if (c < 3) {   // exp of next chunk issues while PV(c) MFMAs execute
#pragma unroll
        for (int mi = 2*c + 2; mi < 2*c + 4; ++mi)
#pragma unroll
          for (int ni = 0; ni < 2; ++ni)
#pragma unroll
            for (int rr = 0; rr < 4; ++rr)
              s[mi][ni][rr] = __builtin_amdgcn_exp2f(s[mi][ni][rr]);
      }
    }

    __syncthreads();   // next K tile landed; all waves done with Ks[cur]
    cur ^= 1;
  }

  // epilogue: Oh = Qh + O/l ; l is in-lane at exactly the row we store
#pragma unroll
  for (int nb = 0; nb < 2; ++nb)
#pragma unroll
    for (int rr = 0; rr < 4; ++rr) {
      int row = wq * 32 + nb * 16 + kg * 4 + rr;
      float linv = 1.0f / lacc[nb][rr];
#pragma unroll
      for (int dvb = 0; dvb < 4; ++dvb) {
        int col = dvb * 16 + rq;
        size_t idx = qkbase + (size_t)(q0 + row) * 1024 + col;
        Ob[idx] = f2bf(oacc[nb][dvb][rr] * linv + bf2f(Qp[idx]));
      }
    }
}

// ---------------------------------------------------------------------------
extern "C" void kernel_launch(void* const* d_in, const int* in_sizes, int n_in,
                              void* d_out, int out_size, void* d_ws, size_t ws_size,
                              hipStream_t stream)
{
  const float* Q  = (const float*)d_in[0];
  const float* K  = (const float*)d_in[1];
  const float* Wq = (const float*)d_in[2];
  const float* bq = (const float*)d_in[3];
  const float* Wk = (const float*)d_in[4];
  const float* bk = (const float*)d_in[5];
  const float* Wv = (const float*)d_in[6];
  const float* bv = (const float*)d_in[7];
  const float* Wo = (const float*)d_in[8];
  const float* bo = (const float*)d_in[9];
  float* Out = (float*)d_out;

  ushort_t* ws = (ushort_t*)d_ws;
  const size_t E = (size_t)8192 * 1024;
  const size_t WSZ = (size_t)1024 * 1024;
  ushort_t* Qb  = ws;            // aliased by Ob after attention
  ushort_t* Kb  = ws + E;
  ushort_t* Qp  = ws + 2*E;
  ushort_t* Kp  = ws + 3*E;
  ushort_t* Vt  = ws + 4*E;      // bf16 V^T, fragment-ordered (Vt2)
  ushort_t* Wqb = ws + 5*E;
  ushort_t* Wkb = ws + 5*E + WSZ;
  ushort_t* Wvb = ws + 5*E + 2*WSZ;
  ushort_t* Wob = ws + 5*E + 3*WSZ;
  ushort_t* Ob  = Qb;

  cvt6<<<dim3(4096, 1, 6), 256, 0, stream>>>(Q, K, Wq, Wk, Wv, Wo,
                                             Qb, Kb, Wqb, Wkb, Wvb, Wob);

  dim3 blk(256);
  gemm_qkv<<<dim3(512, 1, 3), blk, 0, stream>>>(Qb, Kb, Wqb, Wkb, Wvb,
                                                bq, bk, bv, Qp, Kp, Vt);
  attn_kernel<<<dim3(1024), blk, 0, stream>>>(Qp, Kp, Vt, Ob);
  gemm_out<<<dim3(512), blk, 0, stream>>>(Ob, Wob, bo, Out);
}

// Round 7
// 287.745 us; speedup vs baseline: 1.0382x; 1.0382x over previous
//
#include <hip/hip_runtime.h>
#include <cstddef>
#include <cstdint>

// ---------------------------------------------------------------------------
// MAB fused block. B=4 N=M=2048 C=1024 H=16 d=64. bf16 MFMA internally.
// R13: fix R12's vmcnt FIFO-coupling. R12 (V-from-global) regressed because
// vfa group 1 was issued AFTER stage(kt+1): vmcnt is FIFO, so waiting for
// those V loads also waited for the next K tile -> PV stalled ~500cy/tile.
// R13 issues ALL 16 vfa loads BEFORE stage(), so PV's wait is a counted
// vmcnt(4) that never drains the K prefetch. Footprint (LDS 32 KB, VGPR
// ~116) now actually buys 4 blocks/CU of TLP (R11 was LDS-capped at 2).
// Everything else from R12 kept: fragment-ordered Vt2 producer, XCD swizzles,
// l-via-MFMA-ones, cvt_pk pack, zero-C S-MFMA, dbuf 1-barrier K staging.
// ---------------------------------------------------------------------------

typedef unsigned short ushort_t;
typedef __attribute__((ext_vector_type(8))) short bf16x8;
typedef __attribute__((ext_vector_type(4))) float floatx4;
typedef __attribute__((ext_vector_type(2))) float f32x2;
typedef __attribute__((ext_vector_type(2))) __bf16 b16x2;
typedef __attribute__((ext_vector_type(4))) unsigned short us4;

__device__ __forceinline__ ushort_t f2bf(float x) {   // RNE
  union { float f; unsigned u; } v; v.f = x;
  unsigned r = v.u + 0x7FFFu + ((v.u >> 16) & 1u);
  return (ushort_t)(r >> 16);
}
__device__ __forceinline__ float bf2f(ushort_t x) {
  union { unsigned u; float f; } v; v.u = ((unsigned)x) << 16;
  return v.f;
}
// pack two f32 -> [bf16(b):bf16(a)] via +0x8000 + v_perm (round-half-up)
__device__ __forceinline__ unsigned pk2(float a, float b) {
  union { float f; unsigned u; } x, y; x.f = a; y.f = b;
  return __builtin_amdgcn_perm(y.u + 0x8000u, x.u + 0x8000u, 0x07060302u);
}
// pack two f32 -> bf16 pair via compiler (v_cvt_pk_bf16_f32, RNE)
__device__ __forceinline__ unsigned pk2c(float a, float b) {
  union { b16x2 v; unsigned u; } r;
  r.v = __builtin_convertvector((f32x2){a, b}, b16x2);
  return r.u;
}
__device__ __forceinline__ floatx4 mfma16(bf16x8 a, bf16x8 b, floatx4 c) {
  return __builtin_amdgcn_mfma_f32_16x16x32_bf16(a, b, c, 0, 0, 0);
}
__device__ __forceinline__ void gld_lds16(const void* g, void* l) {
  __builtin_amdgcn_global_load_lds(
      (const __attribute__((address_space(1))) unsigned int*)g,
      (__attribute__((address_space(3))) unsigned int*)l, 16, 0, 0);
}

// ---------------------------------------------------------------------------
// f32 -> bf16, 8 elems/thread, 6 tensors by blockIdx.z (Q,K,Wq,Wk,Wv,Wo).
// ---------------------------------------------------------------------------
__global__ void cvt6(const float* __restrict__ i0, const float* __restrict__ i1,
                     const float* __restrict__ i2, const float* __restrict__ i3,
                     const float* __restrict__ i4, const float* __restrict__ i5,
                     ushort_t* __restrict__ o0, ushort_t* __restrict__ o1,
                     ushort_t* __restrict__ o2, ushort_t* __restrict__ o3,
                     ushort_t* __restrict__ o4, ushort_t* __restrict__ o5) {
  int z = blockIdx.z;
  const float* in = z == 0 ? i0 : z == 1 ? i1 : z == 2 ? i2 : z == 3 ? i3 : z == 4 ? i4 : i5;
  ushort_t* out = z == 0 ? o0 : z == 1 ? o1 : z == 2 ? o2 : z == 3 ? o3 : z == 4 ? o4 : o5;
  int n8 = (z < 2) ? 1048576 : 131072;
  int i = blockIdx.x * 256 + threadIdx.x;
  if (i < n8) {
    const float4* p = (const float4*)in + (size_t)i * 2;
    float4 a = p[0], b = p[1];
    uint4 o;
    o.x = pk2(a.x, a.y); o.y = pk2(a.z, a.w);
    o.z = pk2(b.x, b.y); o.w = pk2(b.z, b.w);
    *((uint4*)out + i) = o;
  }
}

// ---------------------------------------------------------------------------
// Fused QKV projections. z=0: Qp; z=1: Kp; z=2: Vt2 (bf16 V^T in attn
// fragment order). Vt2 elem addr = bh*131072 + t*8192 + (c*4+dvb)*512
//   + (kg*16+rq)*8 + hi*4 + rr, holding V^T[dv=dvb*16+rq][kv =
//   t*128 + c*32 + hi*16 + kg*4 + rr]  (bh = b*16+h, dv/h from col).
// 128x128 tile, BK=64, 3-bit XOR chunk swizzle, XCD swizzle on grid.
// ---------------------------------------------------------------------------
__global__ __launch_bounds__(256, 2)
void gemm_qkv(const ushort_t* __restrict__ Qb, const ushort_t* __restrict__ Kb,
              const ushort_t* __restrict__ Wqb, const ushort_t* __restrict__ Wkb,
              const ushort_t* __restrict__ Wvb,
              const float* __restrict__ bq, const float* __restrict__ bk,
              const float* __restrict__ bv,
              ushort_t* __restrict__ Qp, ushort_t* __restrict__ Kp,
              ushort_t* __restrict__ Vt)
{
  const int Kd = 1024, Nn = 1024;
  const int z = blockIdx.z;
  const ushort_t* Ab = (z == 0) ? Qb : Kb;
  const ushort_t* Bw = (z == 0) ? Wqb : (z == 1) ? Wkb : Wvb;
  const float* bias  = (z == 0) ? bq : (z == 1) ? bk : bv;

  __shared__ __align__(16) ushort_t As[128][64];
  __shared__ __align__(16) ushort_t Bs[128][64];
  const int tid = threadIdx.x;
  const int lane = tid & 63, wave = tid >> 6;
  const int wm = (wave >> 1) * 64, wn = (wave & 1) * 64;
  const int rq = lane & 15, kg = lane >> 4;

  // XCD swizzle: each XCD gets a contiguous 8-row-tile A stripe (2 MB in L2)
  const int wg = blockIdx.x, xcd = wg & 7, slot = wg >> 3;   // slot 0..63
  const int by = xcd * 8 + (slot >> 3);                      // 0..63
  const int bx = slot & 7;                                   // 0..7
  const int row0 = by * 128, col0 = bx * 128;

  const int st_sub = lane >> 3;                 // row within 8-row group
  const int st_cs  = (lane & 7) ^ st_sub;       // swizzled source 16B chunk

  floatx4 acc[4][4];
#pragma unroll
  for (int i = 0; i < 4; ++i)
#pragma unroll
    for (int j = 0; j < 4; ++j) acc[i][j] = (floatx4){0.f, 0.f, 0.f, 0.f};

  for (int k0 = 0; k0 < Kd; k0 += 64) {
    __syncthreads();
#pragma unroll
    for (int r = 0; r < 4; ++r) {
      int i = wave * 4 + r;                     // 0..15, 8 rows each
      int row = i * 8 + st_sub;
      gld_lds16(Ab + (size_t)(row0 + row) * Kd + k0 + st_cs * 8, (ushort_t*)As + i * 512);
      gld_lds16(Bw + (size_t)(col0 + row) * Kd + k0 + st_cs * 8, (ushort_t*)Bs + i * 512);
    }
    __syncthreads();
#pragma unroll
    for (int kq = 0; kq < 2; ++kq) {
      bf16x8 af[4], bfr[4];
#pragma unroll
      for (int mi = 0; mi < 4; ++mi)
        af[mi] = *(const bf16x8*)&As[wm + mi*16 + rq][((kq*4 + kg) ^ (rq & 7)) * 8];
#pragma unroll
      for (int ni = 0; ni < 4; ++ni)
        bfr[ni] = *(const bf16x8*)&Bs[wn + ni*16 + rq][((kq*4 + kg) ^ (rq & 7)) * 8];
#pragma unroll
      for (int mi = 0; mi < 4; ++mi)
#pragma unroll
        for (int ni = 0; ni < 4; ++ni)
          acc[mi][ni] = mfma16(af[mi], bfr[ni], acc[mi][ni]);
    }
  }

  float bv4[4];
#pragma unroll
  for (int ni = 0; ni < 4; ++ni) bv4[ni] = bias[col0 + wn + ni*16 + rq];

  if (z < 2) {
    ushort_t* Cb = (z == 0) ? Qp : Kp;
#pragma unroll
    for (int mi = 0; mi < 4; ++mi)
#pragma unroll
      for (int ni = 0; ni < 4; ++ni)
#pragma unroll
        for (int rr = 0; rr < 4; ++rr) {
          int row = row0 + wm + mi*16 + kg*4 + rr;
          int col = col0 + wn + ni*16 + rq;
          Cb[(size_t)row * Nn + col] = f2bf(acc[mi][ni][rr] + bv4[ni]);
        }
  } else {
    // fragment-ordered Vt2 write (see header comment). acc[mi][ni][rr] is
    // V^T[col][kv = row0+wm+mi*16+kg*4+rr]; hi = mi&1.
#pragma unroll
    for (int mi = 0; mi < 4; ++mi)
#pragma unroll
      for (int ni = 0; ni < 4; ++ni) {
        int col = col0 + wn + ni*16 + rq;       // h*64 + dv
        int h = col >> 6, dvb = (col >> 4) & 3; // dv&15 == rq
        int kvg = row0 + wm + (mi >> 1) * 32;   // b*2048 + kv (32-aligned)
        int bI = kvg >> 11, kv = kvg & 2047;
        int t = kv >> 7, c = (kv >> 5) & 3;
        size_t addr = (size_t)(bI * 16 + h) * 131072 + t * 8192
                    + (c * 4 + dvb) * 512 + (kg * 16 + rq) * 8 + (mi & 1) * 4;
        us4 o = { f2bf(acc[mi][ni][0] + bv4[ni]), f2bf(acc[mi][ni][1] + bv4[ni]),
                  f2bf(acc[mi][ni][2] + bv4[ni]), f2bf(acc[mi][ni][3] + bv4[ni]) };
        *(us4*)(Vt + addr) = o;
      }
  }
}

// ---------------------------------------------------------------------------
// Output GEMM: out = bf2f(Ob) + relu(Ob*Wo^T + bo), f32 out. BK=64.
// Grid (512) with the same XCD swizzle as gemm_qkv.
// ---------------------------------------------------------------------------
__global__ __launch_bounds__(256, 2)
void gemm_out(const ushort_t* __restrict__ Ob, const ushort_t* __restrict__ Bw,
              const float* __restrict__ bias, float* __restrict__ Out)
{
  const int Kd = 1024, Nn = 1024;
  __shared__ __align__(16) ushort_t As[128][64];
  __shared__ __align__(16) ushort_t Bs[128][64];
  const int tid = threadIdx.x;
  const int lane = tid & 63, wave = tid >> 6;
  const int wm = (wave >> 1) * 64, wn = (wave & 1) * 64;
  const int rq = lane & 15, kg = lane >> 4;

  const int wg = blockIdx.x, xcd = wg & 7, slot = wg >> 3;
  const int by = xcd * 8 + (slot >> 3);
  const int bx = slot & 7;
  const int row0 = by * 128, col0 = bx * 128;

  const int st_sub = lane >> 3;
  const int st_cs  = (lane & 7) ^ st_sub;

  floatx4 acc[4][4];
#pragma unroll
  for (int i = 0; i < 4; ++i)
#pragma unroll
    for (int j = 0; j < 4; ++j) acc[i][j] = (floatx4){0.f, 0.f, 0.f, 0.f};

  for (int k0 = 0; k0 < Kd; k0 += 64) {
    __syncthreads();
#pragma unroll
    for (int r = 0; r < 4; ++r) {
      int i = wave * 4 + r;
      int row = i * 8 + st_sub;
      gld_lds16(Ob + (size_t)(row0 + row) * Kd + k0 + st_cs * 8, (ushort_t*)As + i * 512);
      gld_lds16(Bw + (size_t)(col0 + row) * Kd + k0 + st_cs * 8, (ushort_t*)Bs + i * 512);
    }
    __syncthreads();
#pragma unroll
    for (int kq = 0; kq < 2; ++kq) {
      bf16x8 af[4], bfr[4];
#pragma unroll
      for (int mi = 0; mi < 4; ++mi)
        af[mi] = *(const bf16x8*)&As[wm + mi*16 + rq][((kq*4 + kg) ^ (rq & 7)) * 8];
#pragma unroll
      for (int ni = 0; ni < 4; ++ni)
        bfr[ni] = *(const bf16x8*)&Bs[wn + ni*16 + rq][((kq*4 + kg) ^ (rq & 7)) * 8];
#pragma unroll
      for (int mi = 0; mi < 4; ++mi)
#pragma unroll
        for (int ni = 0; ni < 4; ++ni)
          acc[mi][ni] = mfma16(af[mi], bfr[ni], acc[mi][ni]);
    }
  }

  float bv4[4];
#pragma unroll
  for (int ni = 0; ni < 4; ++ni) bv4[ni] = bias[col0 + wn + ni*16 + rq];
#pragma unroll
  for (int mi = 0; mi < 4; ++mi)
#pragma unroll
    for (int ni = 0; ni < 4; ++ni)
#pragma unroll
      for (int rr = 0; rr < 4; ++rr) {
        int row = row0 + wm + mi*16 + kg*4 + rr;
        int col = col0 + wn + ni*16 + rq;
        size_t idx = (size_t)row * Nn + col;
        float pre = acc[mi][ni][rr] + bv4[ni];
        Out[idx] = bf2f(Ob[idx]) + (pre > 0.f ? pre : 0.f);
      }
}

// ---------------------------------------------------------------------------
// Flash attention (no-max softmax). BQ=128, BKV=128, d=64, all bf16.
// Wave w owns q rows [w*32, w*32+32); S^T = K*Q^T over the full 128-kv tile
// (K from dbuf LDS), softmax + P-pack in registers, PV with P in-register and
// V^T fragments loaded from fragment-ordered global Vt2 (L2/L1-hot, coalesced
// dwordx4). Load order per tile: vfa x16 FIRST, then stage(kt+1) -> PV's
// vmcnt waits are counted (>=4) and never drain the K prefetch.
// LDS: 2x Ks 16K = 32 KB -> up to 4 blocks/CU. One barrier per K-tile.
// ---------------------------------------------------------------------------
__global__ __launch_bounds__(256, 2)
void attn_kernel(const ushort_t* __restrict__ Qp,
                 const ushort_t* __restrict__ Kp,
                 const ushort_t* __restrict__ Vt,
                 ushort_t* __restrict__ Ob)
{
  const float sc2 = 0.045084439f;  // (1/32) * log2(e)
  const int wg = blockIdx.x, xcd = wg & 7, slot = wg >> 3;   // slot 0..127
  const int bh = xcd * 8 + (slot >> 4);                      // 0..63
  const int qt = slot & 15;                                  // 0..15
  const int b = bh >> 4, h = bh & 15;
  const int q0 = qt * 128;

  __shared__ __align__(16) ushort_t Ks[2][8192];  // K[128][64] per buf

  const int tid = threadIdx.x, lane = tid & 63, wq = tid >> 6;  // wq: q-quarter
  const int rq = lane & 15, kg = lane >> 4;

  const size_t qkbase = (size_t)(b * 2048) * 1024 + h * 64;
  const ushort_t* vbase = Vt + (size_t)bh * 131072 + lane * 8;

  // per-lane staging geometry
  const int sg_sub = lane >> 3;               // row within 8-row group
  const int sg_csk = (lane & 7) ^ sg_sub;     // swizzled 16B chunk (64-col row)

  // stage Q tile (128x64) into Ks[1]
#pragma unroll
  for (int r = 0; r < 4; ++r) {
    int i = wq * 4 + r;
    int row = i * 8 + sg_sub;
    gld_lds16(Qp + qkbase + (size_t)(q0 + row) * 1024 + sg_csk * 8, &Ks[1][i * 512]);
  }
  __syncthreads();

  auto stage = [&](int kt, int bufi) {
    const int kv0 = kt * 128;
#pragma unroll
    for (int r = 0; r < 4; ++r) {
      int i = wq * 4 + r;
      int rowk = i * 8 + sg_sub;
      gld_lds16(Kp + qkbase + (size_t)(kv0 + rowk) * 1024 + sg_csk * 8,
                &Ks[bufi][i * 512]);
    }
  };
  stage(0, 0);

  // preload Q B-frags scaled by sc2 from Ks[1]: aq[ni][kq], q = wq*32+ni*16+rq
  bf16x8 aq[2][2];
#pragma unroll
  for (int ni = 0; ni < 2; ++ni)
#pragma unroll
    for (int kq = 0; kq < 2; ++kq) {
      int row = wq * 32 + ni * 16 + rq;
      int ch = (kq * 4 + kg) ^ (rq & 7);
      bf16x8 t = *(const bf16x8*)&Ks[1][row * 64 + ch * 8];
#pragma unroll
      for (int e = 0; e < 8; ++e)
        t[e] = (short)f2bf(bf2f((ushort_t)t[e]) * sc2);
      aq[ni][kq] = t;
    }

  // ones B-operand for the l row-sum MFMA (permutation-invariant)
  bf16x8 ones;
#pragma unroll
  for (int e = 0; e < 8; ++e) ones[e] = (short)0x3F80;

  const floatx4 zf = (floatx4){0.f, 0.f, 0.f, 0.f};  // loop-invariant zero C

  floatx4 oacc[2][4];
  floatx4 lacc[2];
#pragma unroll
  for (int nb = 0; nb < 2; ++nb) {
    lacc[nb] = (floatx4){0.f,0.f,0.f,0.f};
#pragma unroll
    for (int dvb = 0; dvb < 4; ++dvb) oacc[nb][dvb] = (floatx4){0.f,0.f,0.f,0.f};
  }

  __syncthreads();   // tile 0 landed; all waves done reading Q from Ks[1]

  int cur = 0;
#pragma unroll 2
  for (int kt = 0; kt < 16; ++kt) {
    const ushort_t* vtile = vbase + kt * 8192;

    // ALL V fragment loads first (oldest in vmcnt FIFO) -- L2/L1-hot,
    // coalesced dwordx4; S-phase covers their latency.
    bf16x8 vfa[16];
#pragma unroll
    for (int j = 0; j < 16; ++j)
      vfa[j] = *(const bf16x8*)(vtile + j * 512);

    // THEN issue next tile's K stage (newest in FIFO): waiting on vfa is a
    // counted vmcnt(>=4) and never drains these.
    if (kt < 15) stage(kt + 1, cur ^ 1);

    // S^T = K * Q^T  (mi = kv block 0..7, ni = q block 0..1)
    floatx4 s[8][2];
    __builtin_amdgcn_s_setprio(1);
    {
      bf16x8 ak[8];
#pragma unroll
      for (int mi = 0; mi < 8; ++mi)
        ak[mi] = *(const bf16x8*)&Ks[cur][(mi * 16 + rq) * 64 + ((kg ^ (rq & 7)) * 8)];
#pragma unroll
      for (int mi = 0; mi < 8; ++mi)
#pragma unroll
        for (int ni = 0; ni < 2; ++ni)
          s[mi][ni] = mfma16(ak[mi], aq[ni][0], zf);      // zero-C, no v_movs
#pragma unroll
      for (int mi = 0; mi < 8; ++mi)
        ak[mi] = *(const bf16x8*)&Ks[cur][(mi * 16 + rq) * 64 + (((4 + kg) ^ (rq & 7)) * 8)];
#pragma unroll
      for (int mi = 0; mi < 8; ++mi)
#pragma unroll
        for (int ni = 0; ni < 2; ++ni)
          s[mi][ni] = mfma16(ak[mi], aq[ni][1], s[mi][ni]);
    }
    __builtin_amdgcn_s_setprio(0);

    // exp chunk 0 (mi 0,1); remaining chunks overlap PV MFMAs below
#pragma unroll
    for (int mi = 0; mi < 2; ++mi)
#pragma unroll
      for (int ni = 0; ni < 2; ++ni)
#pragma unroll
        for (int rr = 0; rr < 4; ++rr)
          s[mi][ni][rr] = __builtin_amdgcn_exp2f(s[mi][ni][rr]);

    // O += P V ; l += P 1 : per kv-32 chunk c: pack -> MFMA -> exp(next chunk)
#pragma unroll
    for (int c = 0; c < 4; ++c) {
      union { unsigned u[4]; bf16x8 v; } pa0, pa1;
      pa0.u[0] = pk2c(s[2*c  ][0][0], s[2*c  ][0][1]);
      pa0.u[1] = pk2c(s[2*c  ][0][2], s[2*c  ][0][3]);
      pa0.u[2] = pk2c(s[2*c+1][0][0], s[2*c+1][0][1]);
      pa0.u[3] = pk2c(s[2*c+1][0][2], s[2*c+1][0][3]);
      pa1.u[0] = pk2c(s[2*c  ][1][0], s[2*c  ][1][1]);
      pa1.u[1] = pk2c(s[2*c  ][1][2], s[2*c  ][1][3]);
      pa1.u[2] = pk2c(s[2*c+1][1][0], s[2*c+1][1][1]);
      pa1.u[3] = pk2c(s[2*c+1][1][2], s[2*c+1][1][3]);
      __builtin_amdgcn_s_setprio(1);
#pragma unroll
      for (int dvb = 0; dvb < 4; ++dvb) {
        oacc[0][dvb] = mfma16(pa0.v, vfa[c*4+dvb], oacc[0][dvb]);
        oacc[1][dvb] = mfma16(pa1.v, vfa[c*4+dvb], oacc[1][dvb]);
      }
      lacc[0] = mfma16(pa0.v, ones, lacc[0]);
      lacc[1] = mfma16(pa1.v, ones, lacc[1]);
      __builtin_amdgcn_s_setprio(0);
      if (c < 3) {   // exp of next chunk issues while PV(c) MFMAs execute
#pragma unroll
        for (int mi = 2*c + 2; mi < 2*c + 4; ++mi)
#pragma unroll
          for (int ni = 0; ni < 2; ++ni)
#pragma unroll
            for (int rr = 0; rr < 4; ++rr)
              s[mi][ni][rr] = __builtin_amdgcn_exp2f(s[mi][ni][rr]);
      }
    }

    __syncthreads();   // next K tile landed; all waves done with Ks[cur]
    cur ^= 1;
  }

  // epilogue: Oh = Qh + O/l ; l is in-lane at exactly the row we store
#pragma unroll
  for (int nb = 0; nb < 2; ++nb)
#pragma unroll
    for (int rr = 0; rr < 4; ++rr) {
      int row = wq * 32 + nb * 16 + kg * 4 + rr;
      float linv = 1.0f / lacc[nb][rr];
#pragma unroll
      for (int dvb = 0; dvb < 4; ++dvb) {
        int col = dvb * 16 + rq;
        size_t idx = qkbase + (size_t)(q0 + row) * 1024 + col;
        Ob[idx] = f2bf(oacc[nb][dvb][rr] * linv + bf2f(Qp[idx]));
      }
    }
}

// ---------------------------------------------------------------------------
extern "C" void kernel_launch(void* const* d_in, const int* in_sizes, int n_in,
                              void* d_out, int out_size, void* d_ws, size_t ws_size,
                              hipStream_t stream)
{
  const float* Q  = (const float*)d_in[0];
  const float* K  = (const float*)d_in[1];
  const float* Wq = (const float*)d_in[2];
  const float* bq = (const float*)d_in[3];
  const float* Wk = (const float*)d_in[4];
  const float* bk = (const float*)d_in[5];
  const float* Wv = (const float*)d_in[6];
  const float* bv = (const float*)d_in[7];
  const float* Wo = (const float*)d_in[8];
  const float* bo = (const float*)d_in[9];
  float* Out = (float*)d_out;

  ushort_t* ws = (ushort_t*)d_ws;
  const size_t E = (size_t)8192 * 1024;
  const size_t WSZ = (size_t)1024 * 1024;
  ushort_t* Qb  = ws;            // aliased by Ob after attention
  ushort_t* Kb  = ws + E;
  ushort_t* Qp  = ws + 2*E;
  ushort_t* Kp  = ws + 3*E;
  ushort_t* Vt  = ws + 4*E;      // bf16 V^T, fragment-ordered (Vt2)
  ushort_t* Wqb = ws + 5*E;
  ushort_t* Wkb = ws + 5*E + WSZ;
  ushort_t* Wvb = ws + 5*E + 2*WSZ;
  ushort_t* Wob = ws + 5*E + 3*WSZ;
  ushort_t* Ob  = Qb;

  cvt6<<<dim3(4096, 1, 6), 256, 0, stream>>>(Q, K, Wq, Wk, Wv, Wo,
                                             Qb, Kb, Wqb, Wkb, Wvb, Wob);

  dim3 blk(256);
  gemm_qkv<<<dim3(512, 1, 3), blk, 0, stream>>>(Qb, Kb, Wqb, Wkb, Wvb,
                                                bq, bk, bv, Qp, Kp, Vt);
  attn_kernel<<<dim3(1024), blk, 0, stream>>>(Qp, Kp, Vt, Ob);
  gemm_out<<<dim3(512), blk, 0, stream>>>(Ob, Wob, bo, Out);
}

// Round 8
// 277.498 us; speedup vs baseline: 1.0765x; 1.0369x over previous
//
#include <hip/hip_runtime.h>
#include <cstddef>
#include <cstdint>

// ---------------------------------------------------------------------------
// MAB fused block. B=4 N=M=2048 C=1024 H=16 d=64. bf16 MFMA internally.
// R14: wall-clock ledger shows attn = 81.6us of 287.7 -> ~206us lives in
// cvt6/gemm_qkv/gemm_out (each < 81us so never in top-5, jointly dominant;
// ideal sum ~35us). Their disease is the serial 2-barrier-per-K-step staging
// (full L2/HBM latency exposed 16x). This round: T3-minimum double-buffered
// staging in BOTH GEMMs (same pattern as attn R8): stage(k+1 -> buf^1) BEFORE
// compute(buf), ONE barrier per K-step (implicit vmcnt(0) drain = next tile
// landed + all waves done reading buf). LDS 32->64 KB, grid 512 = 2 blocks/CU
// exactly matches cap. attn unchanged from R13 (81.6us).
// ---------------------------------------------------------------------------

typedef unsigned short ushort_t;
typedef __attribute__((ext_vector_type(8))) short bf16x8;
typedef __attribute__((ext_vector_type(4))) float floatx4;
typedef __attribute__((ext_vector_type(2))) float f32x2;
typedef __attribute__((ext_vector_type(2))) __bf16 b16x2;
typedef __attribute__((ext_vector_type(4))) unsigned short us4;

__device__ __forceinline__ ushort_t f2bf(float x) {   // RNE
  union { float f; unsigned u; } v; v.f = x;
  unsigned r = v.u + 0x7FFFu + ((v.u >> 16) & 1u);
  return (ushort_t)(r >> 16);
}
__device__ __forceinline__ float bf2f(ushort_t x) {
  union { unsigned u; float f; } v; v.u = ((unsigned)x) << 16;
  return v.f;
}
// pack two f32 -> [bf16(b):bf16(a)] via +0x8000 + v_perm (round-half-up)
__device__ __forceinline__ unsigned pk2(float a, float b) {
  union { float f; unsigned u; } x, y; x.f = a; y.f = b;
  return __builtin_amdgcn_perm(y.u + 0x8000u, x.u + 0x8000u, 0x07060302u);
}
// pack two f32 -> bf16 pair via compiler (v_cvt_pk_bf16_f32, RNE)
__device__ __forceinline__ unsigned pk2c(float a, float b) {
  union { b16x2 v; unsigned u; } r;
  r.v = __builtin_convertvector((f32x2){a, b}, b16x2);
  return r.u;
}
__device__ __forceinline__ floatx4 mfma16(bf16x8 a, bf16x8 b, floatx4 c) {
  return __builtin_amdgcn_mfma_f32_16x16x32_bf16(a, b, c, 0, 0, 0);
}
__device__ __forceinline__ void gld_lds16(const void* g, void* l) {
  __builtin_amdgcn_global_load_lds(
      (const __attribute__((address_space(1))) unsigned int*)g,
      (__attribute__((address_space(3))) unsigned int*)l, 16, 0, 0);
}

// ---------------------------------------------------------------------------
// f32 -> bf16, 8 elems/thread, 6 tensors by blockIdx.z (Q,K,Wq,Wk,Wv,Wo).
// ---------------------------------------------------------------------------
__global__ void cvt6(const float* __restrict__ i0, const float* __restrict__ i1,
                     const float* __restrict__ i2, const float* __restrict__ i3,
                     const float* __restrict__ i4, const float* __restrict__ i5,
                     ushort_t* __restrict__ o0, ushort_t* __restrict__ o1,
                     ushort_t* __restrict__ o2, ushort_t* __restrict__ o3,
                     ushort_t* __restrict__ o4, ushort_t* __restrict__ o5) {
  int z = blockIdx.z;
  const float* in = z == 0 ? i0 : z == 1 ? i1 : z == 2 ? i2 : z == 3 ? i3 : z == 4 ? i4 : i5;
  ushort_t* out = z == 0 ? o0 : z == 1 ? o1 : z == 2 ? o2 : z == 3 ? o3 : z == 4 ? o4 : o5;
  int n8 = (z < 2) ? 1048576 : 131072;
  int i = blockIdx.x * 256 + threadIdx.x;
  if (i < n8) {
    const float4* p = (const float4*)in + (size_t)i * 2;
    float4 a = p[0], b = p[1];
    uint4 o;
    o.x = pk2(a.x, a.y); o.y = pk2(a.z, a.w);
    o.z = pk2(b.x, b.y); o.w = pk2(b.z, b.w);
    *((uint4*)out + i) = o;
  }
}

// ---------------------------------------------------------------------------
// Fused QKV projections. z=0: Qp; z=1: Kp; z=2: Vt2 (bf16 V^T in attn
// fragment order). Vt2 elem addr = bh*131072 + t*8192 + (c*4+dvb)*512
//   + (kg*16+rq)*8 + hi*4 + rr.
// 128x128 tile, BK=64, 3-bit XOR chunk swizzle, XCD swizzle on grid.
// R14: double-buffered staging, ONE barrier per K-step.
// ---------------------------------------------------------------------------
__global__ __launch_bounds__(256, 2)
void gemm_qkv(const ushort_t* __restrict__ Qb, const ushort_t* __restrict__ Kb,
              const ushort_t* __restrict__ Wqb, const ushort_t* __restrict__ Wkb,
              const ushort_t* __restrict__ Wvb,
              const float* __restrict__ bq, const float* __restrict__ bk,
              const float* __restrict__ bv,
              ushort_t* __restrict__ Qp, ushort_t* __restrict__ Kp,
              ushort_t* __restrict__ Vt)
{
  const int Kd = 1024, Nn = 1024;
  const int z = blockIdx.z;
  const ushort_t* Ab = (z == 0) ? Qb : Kb;
  const ushort_t* Bw = (z == 0) ? Wqb : (z == 1) ? Wkb : Wvb;
  const float* bias  = (z == 0) ? bq : (z == 1) ? bk : bv;

  __shared__ __align__(16) ushort_t As[2][8192];
  __shared__ __align__(16) ushort_t Bs[2][8192];
  const int tid = threadIdx.x;
  const int lane = tid & 63, wave = tid >> 6;
  const int wm = (wave >> 1) * 64, wn = (wave & 1) * 64;
  const int rq = lane & 15, kg = lane >> 4;

  // XCD swizzle: each XCD gets a contiguous 8-row-tile A stripe (2 MB in L2)
  const int wg = blockIdx.x, xcd = wg & 7, slot = wg >> 3;   // slot 0..63
  const int by = xcd * 8 + (slot >> 3);                      // 0..63
  const int bx = slot & 7;                                   // 0..7
  const int row0 = by * 128, col0 = bx * 128;

  const int st_sub = lane >> 3;                 // row within 8-row group
  const int st_cs  = (lane & 7) ^ st_sub;       // swizzled source 16B chunk

  auto stageAB = [&](int k0, int bufi) {
#pragma unroll
    for (int r = 0; r < 4; ++r) {
      int i = wave * 4 + r;                     // 0..15, 8 rows each
      int row = i * 8 + st_sub;
      gld_lds16(Ab + (size_t)(row0 + row) * Kd + k0 + st_cs * 8, &As[bufi][i * 512]);
      gld_lds16(Bw + (size_t)(col0 + row) * Kd + k0 + st_cs * 8, &Bs[bufi][i * 512]);
    }
  };

  floatx4 acc[4][4];
#pragma unroll
  for (int i = 0; i < 4; ++i)
#pragma unroll
    for (int j = 0; j < 4; ++j) acc[i][j] = (floatx4){0.f, 0.f, 0.f, 0.f};

  stageAB(0, 0);
  __syncthreads();   // tile 0 landed

  int cur = 0;
  for (int kt = 0; kt < 16; ++kt) {
    if (kt < 15) stageAB((kt + 1) * 64, cur ^ 1);   // overlaps compute below
#pragma unroll
    for (int kq = 0; kq < 2; ++kq) {
      bf16x8 af[4], bfr[4];
#pragma unroll
      for (int mi = 0; mi < 4; ++mi)
        af[mi] = *(const bf16x8*)&As[cur][(wm + mi*16 + rq) * 64 + (((kq*4 + kg) ^ (rq & 7)) * 8)];
#pragma unroll
      for (int ni = 0; ni < 4; ++ni)
        bfr[ni] = *(const bf16x8*)&Bs[cur][(wn + ni*16 + rq) * 64 + (((kq*4 + kg) ^ (rq & 7)) * 8)];
#pragma unroll
      for (int mi = 0; mi < 4; ++mi)
#pragma unroll
        for (int ni = 0; ni < 4; ++ni)
          acc[mi][ni] = mfma16(af[mi], bfr[ni], acc[mi][ni]);
    }
    __syncthreads();   // next tile landed; all waves done reading buf[cur]
    cur ^= 1;
  }

  float bv4[4];
#pragma unroll
  for (int ni = 0; ni < 4; ++ni) bv4[ni] = bias[col0 + wn + ni*16 + rq];

  if (z < 2) {
    ushort_t* Cb = (z == 0) ? Qp : Kp;
#pragma unroll
    for (int mi = 0; mi < 4; ++mi)
#pragma unroll
      for (int ni = 0; ni < 4; ++ni)
#pragma unroll
        for (int rr = 0; rr < 4; ++rr) {
          int row = row0 + wm + mi*16 + kg*4 + rr;
          int col = col0 + wn + ni*16 + rq;
          Cb[(size_t)row * Nn + col] = f2bf(acc[mi][ni][rr] + bv4[ni]);
        }
  } else {
    // fragment-ordered Vt2 write. acc[mi][ni][rr] is V^T[col][kv]; hi = mi&1.
#pragma unroll
    for (int mi = 0; mi < 4; ++mi)
#pragma unroll
      for (int ni = 0; ni < 4; ++ni) {
        int col = col0 + wn + ni*16 + rq;       // h*64 + dv
        int h = col >> 6, dvb = (col >> 4) & 3; // dv&15 == rq
        int kvg = row0 + wm + (mi >> 1) * 32;   // b*2048 + kv (32-aligned)
        int bI = kvg >> 11, kv = kvg & 2047;
        int t = kv >> 7, c = (kv >> 5) & 3;
        size_t addr = (size_t)(bI * 16 + h) * 131072 + t * 8192
                    + (c * 4 + dvb) * 512 + (kg * 16 + rq) * 8 + (mi & 1) * 4;
        us4 o = { f2bf(acc[mi][ni][0] + bv4[ni]), f2bf(acc[mi][ni][1] + bv4[ni]),
                  f2bf(acc[mi][ni][2] + bv4[ni]), f2bf(acc[mi][ni][3] + bv4[ni]) };
        *(us4*)(Vt + addr) = o;
      }
  }
}

// ---------------------------------------------------------------------------
// Output GEMM: out = bf2f(Ob) + relu(Ob*Wo^T + bo), f32 out. BK=64.
// Grid (512) with XCD swizzle. R14: double-buffered, ONE barrier per K-step.
// ---------------------------------------------------------------------------
__global__ __launch_bounds__(256, 2)
void gemm_out(const ushort_t* __restrict__ Ob, const ushort_t* __restrict__ Bw,
              const float* __restrict__ bias, float* __restrict__ Out)
{
  const int Kd = 1024, Nn = 1024;
  __shared__ __align__(16) ushort_t As[2][8192];
  __shared__ __align__(16) ushort_t Bs[2][8192];
  const int tid = threadIdx.x;
  const int lane = tid & 63, wave = tid >> 6;
  const int wm = (wave >> 1) * 64, wn = (wave & 1) * 64;
  const int rq = lane & 15, kg = lane >> 4;

  const int wg = blockIdx.x, xcd = wg & 7, slot = wg >> 3;
  const int by = xcd * 8 + (slot >> 3);
  const int bx = slot & 7;
  const int row0 = by * 128, col0 = bx * 128;

  const int st_sub = lane >> 3;
  const int st_cs  = (lane & 7) ^ st_sub;

  auto stageAB = [&](int k0, int bufi) {
#pragma unroll
    for (int r = 0; r < 4; ++r) {
      int i = wave * 4 + r;
      int row = i * 8 + st_sub;
      gld_lds16(Ob + (size_t)(row0 + row) * Kd + k0 + st_cs * 8, &As[bufi][i * 512]);
      gld_lds16(Bw + (size_t)(col0 + row) * Kd + k0 + st_cs * 8, &Bs[bufi][i * 512]);
    }
  };

  floatx4 acc[4][4];
#pragma unroll
  for (int i = 0; i < 4; ++i)
#pragma unroll
    for (int j = 0; j < 4; ++j) acc[i][j] = (floatx4){0.f, 0.f, 0.f, 0.f};

  stageAB(0, 0);
  __syncthreads();

  int cur = 0;
  for (int kt = 0; kt < 16; ++kt) {
    if (kt < 15) stageAB((kt + 1) * 64, cur ^ 1);
#pragma unroll
    for (int kq = 0; kq < 2; ++kq) {
      bf16x8 af[4], bfr[4];
#pragma unroll
      for (int mi = 0; mi < 4; ++mi)
        af[mi] = *(const bf16x8*)&As[cur][(wm + mi*16 + rq) * 64 + (((kq*4 + kg) ^ (rq & 7)) * 8)];
#pragma unroll
      for (int ni = 0; ni < 4; ++ni)
        bfr[ni] = *(const bf16x8*)&Bs[cur][(wn + ni*16 + rq) * 64 + (((kq*4 + kg) ^ (rq & 7)) * 8)];
#pragma unroll
      for (int mi = 0; mi < 4; ++mi)
#pragma unroll
        for (int ni = 0; ni < 4; ++ni)
          acc[mi][ni] = mfma16(af[mi], bfr[ni], acc[mi][ni]);
    }
    __syncthreads();
    cur ^= 1;
  }

  float bv4[4];
#pragma unroll
  for (int ni = 0; ni < 4; ++ni) bv4[ni] = bias[col0 + wn + ni*16 + rq];
#pragma unroll
  for (int mi = 0; mi < 4; ++mi)
#pragma unroll
    for (int ni = 0; ni < 4; ++ni)
#pragma unroll
      for (int rr = 0; rr < 4; ++rr) {
        int row = row0 + wm + mi*16 + kg*4 + rr;
        int col = col0 + wn + ni*16 + rq;
        size_t idx = (size_t)row * Nn + col;
        float pre = acc[mi][ni][rr] + bv4[ni];
        Out[idx] = bf2f(Ob[idx]) + (pre > 0.f ? pre : 0.f);
      }
}

// ---------------------------------------------------------------------------
// Flash attention (no-max softmax). BQ=128, BKV=128, d=64, all bf16.
// Unchanged from R13 (81.6us): K dbuf in LDS, V from fragment-ordered global,
// in-register softmax, l-via-MFMA-ones, one barrier per K-tile.
// ---------------------------------------------------------------------------
__global__ __launch_bounds__(256, 2)
void attn_kernel(const ushort_t* __restrict__ Qp,
                 const ushort_t* __restrict__ Kp,
                 const ushort_t* __restrict__ Vt,
                 ushort_t* __restrict__ Ob)
{
  const float sc2 = 0.045084439f;  // (1/32) * log2(e)
  const int wg = blockIdx.x, xcd = wg & 7, slot = wg >> 3;   // slot 0..127
  const int bh = xcd * 8 + (slot >> 4);                      // 0..63
  const int qt = slot & 15;                                  // 0..15
  const int b = bh >> 4, h = bh & 15;
  const int q0 = qt * 128;

  __shared__ __align__(16) ushort_t Ks[2][8192];  // K[128][64] per buf

  const int tid = threadIdx.x, lane = tid & 63, wq = tid >> 6;  // wq: q-quarter
  const int rq = lane & 15, kg = lane >> 4;

  const size_t qkbase = (size_t)(b * 2048) * 1024 + h * 64;
  const ushort_t* vbase = Vt + (size_t)bh * 131072 + lane * 8;

  // per-lane staging geometry
  const int sg_sub = lane >> 3;               // row within 8-row group
  const int sg_csk = (lane & 7) ^ sg_sub;     // swizzled 16B chunk (64-col row)

  // stage Q tile (128x64) into Ks[1]
#pragma unroll
  for (int r = 0; r < 4; ++r) {
    int i = wq * 4 + r;
    int row = i * 8 + sg_sub;
    gld_lds16(Qp + qkbase + (size_t)(q0 + row) * 1024 + sg_csk * 8, &Ks[1][i * 512]);
  }
  __syncthreads();

  auto stage = [&](int kt, int bufi) {
    const int kv0 = kt * 128;
#pragma unroll
    for (int r = 0; r < 4; ++r) {
      int i = wq * 4 + r;
      int rowk = i * 8 + sg_sub;
      gld_lds16(Kp + qkbase + (size_t)(kv0 + rowk) * 1024 + sg_csk * 8,
                &Ks[bufi][i * 512]);
    }
  };
  stage(0, 0);

  // preload Q B-frags scaled by sc2 from Ks[1]: aq[ni][kq], q = wq*32+ni*16+rq
  bf16x8 aq[2][2];
#pragma unroll
  for (int ni = 0; ni < 2; ++ni)
#pragma unroll
    for (int kq = 0; kq < 2; ++kq) {
      int row = wq * 32 + ni * 16 + rq;
      int ch = (kq * 4 + kg) ^ (rq & 7);
      bf16x8 t = *(const bf16x8*)&Ks[1][row * 64 + ch * 8];
#pragma unroll
      for (int e = 0; e < 8; ++e)
        t[e] = (short)f2bf(bf2f((ushort_t)t[e]) * sc2);
      aq[ni][kq] = t;
    }

  // ones B-operand for the l row-sum MFMA (permutation-invariant)
  bf16x8 ones;
#pragma unroll
  for (int e = 0; e < 8; ++e) ones[e] = (short)0x3F80;

  const floatx4 zf = (floatx4){0.f, 0.f, 0.f, 0.f};  // loop-invariant zero C

  floatx4 oacc[2][4];
  floatx4 lacc[2];
#pragma unroll
  for (int nb = 0; nb < 2; ++nb) {
    lacc[nb] = (floatx4){0.f,0.f,0.f,0.f};
#pragma unroll
    for (int dvb = 0; dvb < 4; ++dvb) oacc[nb][dvb] = (floatx4){0.f,0.f,0.f,0.f};
  }

  __syncthreads();   // tile 0 landed; all waves done reading Q from Ks[1]

  int cur = 0;
#pragma unroll 2
  for (int kt = 0; kt < 16; ++kt) {
    const ushort_t* vtile = vbase + kt * 8192;

    // ALL V fragment loads first (oldest in vmcnt FIFO) -- L2/L1-hot,
    // coalesced dwordx4; S-phase covers their latency.
    bf16x8 vfa[16];
#pragma unroll
    for (int j = 0; j < 16; ++j)
      vfa[j] = *(const bf16x8*)(vtile + j * 512);

    // THEN issue next tile's K stage (newest in FIFO): waiting on vfa is a
    // counted vmcnt(>=4) and never drains these.
    if (kt < 15) stage(kt + 1, cur ^ 1);

    // S^T = K * Q^T  (mi = kv block 0..7, ni = q block 0..1)
    floatx4 s[8][2];
    __builtin_amdgcn_s_setprio(1);
    {
      bf16x8 ak[8];
#pragma unroll
      for (int mi = 0; mi < 8; ++mi)
        ak[mi] = *(const bf16x8*)&Ks[cur][(mi * 16 + rq) * 64 + ((kg ^ (rq & 7)) * 8)];
#pragma unroll
      for (int mi = 0; mi < 8; ++mi)
#pragma unroll
        for (int ni = 0; ni < 2; ++ni)
          s[mi][ni] = mfma16(ak[mi], aq[ni][0], zf);      // zero-C, no v_movs
#pragma unroll
      for (int mi = 0; mi < 8; ++mi)
        ak[mi] = *(const bf16x8*)&Ks[cur][(mi * 16 + rq) * 64 + (((4 + kg) ^ (rq & 7)) * 8)];
#pragma unroll
      for (int mi = 0; mi < 8; ++mi)
#pragma unroll
        for (int ni = 0; ni < 2; ++ni)
          s[mi][ni] = mfma16(ak[mi], aq[ni][1], s[mi][ni]);
    }
    __builtin_amdgcn_s_setprio(0);

    // exp chunk 0 (mi 0,1); remaining chunks overlap PV MFMAs below
#pragma unroll
    for (int mi = 0; mi < 2; ++mi)
#pragma unroll
      for (int ni = 0; ni < 2; ++ni)
#pragma unroll
        for (int rr = 0; rr < 4; ++rr)
          s[mi][ni][rr] = __builtin_amdgcn_exp2f(s[mi][ni][rr]);

    // O += P V ; l += P 1 : per kv-32 chunk c: pack -> MFMA -> exp(next chunk)
#pragma unroll
    for (int c = 0; c < 4; ++c) {
      union { unsigned u[4]; bf16x8 v; } pa0, pa1;
      pa0.u[0] = pk2c(s[2*c  ][0][0], s[2*c  ][0][1]);
      pa0.u[1] = pk2c(s[2*c  ][0][2], s[2*c  ][0][3]);
      pa0.u[2] = pk2c(s[2*c+1][0][0], s[2*c+1][0][1]);
      pa0.u[3] = pk2c(s[2*c+1][0][2], s[2*c+1][0][3]);
      pa1.u[0] = pk2c(s[2*c  ][1][0], s[2*c  ][1][1]);
      pa1.u[1] = pk2c(s[2*c  ][1][2], s[2*c  ][1][3]);
      pa1.u[2] = pk2c(s[2*c+1][1][0], s[2*c+1][1][1]);
      pa1.u[3] = pk2c(s[2*c+1][1][2], s[2*c+1][1][3]);
      __builtin_amdgcn_s_setprio(1);
#pragma unroll
      for (int dvb = 0; dvb < 4; ++dvb) {
        oacc[0][dvb] = mfma16(pa0.v, vfa[c*4+dvb], oacc[0][dvb]);
        oacc[1][dvb] = mfma16(pa1.v, vfa[c*4+dvb], oacc[1][dvb]);
      }
      lacc[0] = mfma16(pa0.v, ones, lacc[0]);
      lacc[1] = mfma16(pa1.v, ones, lacc[1]);
      __builtin_amdgcn_s_setprio(0);
      if (c < 3) {   // exp of next chunk issues while PV(c) MFMAs execute
#pragma unroll
        for (int mi = 2*c + 2; mi < 2*c + 4; ++mi)
#pragma unroll
          for (int ni = 0; ni < 2; ++ni)
#pragma unroll
            for (int rr = 0; rr < 4; ++rr)
              s[mi][ni][rr] = __builtin_amdgcn_exp2f(s[mi][ni][rr]);
      }
    }

    __syncthreads();   // next K tile landed; all waves done with Ks[cur]
    cur ^= 1;
  }

  // epilogue: Oh = Qh + O/l ; l is in-lane at exactly the row we store
#pragma unroll
  for (int nb = 0; nb < 2; ++nb)
#pragma unroll
    for (int rr = 0; rr < 4; ++rr) {
      int row = wq * 32 + nb * 16 + kg * 4 + rr;
      float linv = 1.0f / lacc[nb][rr];
#pragma unroll
      for (int dvb = 0; dvb < 4; ++dvb) {
        int col = dvb * 16 + rq;
        size_t idx = qkbase + (size_t)(q0 + row) * 1024 + col;
        Ob[idx] = f2bf(oacc[nb][dvb][rr] * linv + bf2f(Qp[idx]));
      }
    }
}

// ---------------------------------------------------------------------------
extern "C" void kernel_launch(void* const* d_in, const int* in_sizes, int n_in,
                              void* d_out, int out_size, void* d_ws, size_t ws_size,
                              hipStream_t stream)
{
  const float* Q  = (const float*)d_in[0];
  const float* K  = (const float*)d_in[1];
  const float* Wq = (const float*)d_in[2];
  const float* bq = (const float*)d_in[3];
  const float* Wk = (const float*)d_in[4];
  const float* bk = (const float*)d_in[5];
  const float* Wv = (const float*)d_in[6];
  const float* bv = (const float*)d_in[7];
  const float* Wo = (const float*)d_in[8];
  const float* bo = (const float*)d_in[9];
  float* Out = (float*)d_out;

  ushort_t* ws = (ushort_t*)d_ws;
  const size_t E = (size_t)8192 * 1024;
  const size_t WSZ = (size_t)1024 * 1024;
  ushort_t* Qb  = ws;            // aliased by Ob after attention
  ushort_t* Kb  = ws + E;
  ushort_t* Qp  = ws + 2*E;
  ushort_t* Kp  = ws + 3*E;
  ushort_t* Vt  = ws + 4*E;      // bf16 V^T, fragment-ordered (Vt2)
  ushort_t* Wqb = ws + 5*E;
  ushort_t* Wkb = ws + 5*E + WSZ;
  ushort_t* Wvb = ws + 5*E + 2*WSZ;
  ushort_t* Wob = ws + 5*E + 3*WSZ;
  ushort_t* Ob  = Qb;

  cvt6<<<dim3(4096, 1, 6), 256, 0, stream>>>(Q, K, Wq, Wk, Wv, Wo,
                                             Qb, Kb, Wqb, Wkb, Wvb, Wob);

  dim3 blk(256);
  gemm_qkv<<<dim3(512, 1, 3), blk, 0, stream>>>(Qb, Kb, Wqb, Wkb, Wvb,
                                                bq, bk, bv, Qp, Kp, Vt);
  attn_kernel<<<dim3(1024), blk, 0, stream>>>(Qp, Kp, Vt, Ob);
  gemm_out<<<dim3(512), blk, 0, stream>>>(Ob, Wob, bo, Out);
}